// Round 2
// baseline (2134.573 us; speedup 1.0000x reference)
//
#include <hip/hip_runtime.h>
#include <hip/hip_cooperative_groups.h>
#include <math.h>

namespace cg = cooperative_groups;

#define CF 768
#define MM 32
#define HW 784
#define MCF 24576
#define BETA 0.05f

__device__ __forceinline__ float dot4(float4 a, float4 b, float acc) {
    acc = fmaf(a.x, b.x, acc); acc = fmaf(a.y, b.y, acc);
    acc = fmaf(a.z, b.z, acc); acc = fmaf(a.w, b.w, acc);
    return acc;
}

// ================= kA2: V[b][m][c] = (1/784) sum_hw A[b][m][hw] * F[b][c][hw]
// grid 256 = 32 b x 8 ctiles(96c); 256 thr; hw chunks of 56 (14 float4), double-buffered
#define KA_CT 96
#define KA_PAD 15   // padded float4 stride per row

__global__ __launch_bounds__(256) void kA2(const float* __restrict__ F,
                                           const float* __restrict__ A,
                                           float* __restrict__ V) {
    __shared__ float4 Fs[2][KA_CT][KA_PAD];   // 46080 B
    __shared__ float4 As[2][32][KA_PAD];      // 15360 B
    const int b = blockIdx.x >> 3;
    const int cbase = (blockIdx.x & 7) * KA_CT;
    const int t = threadIdx.x;
    const int tx = t & 31;        // 3 c each
    const int ty = t >> 5;        // 4 m each
    const int c0 = tx * 3, m0 = ty * 4;
    const float4* F4 = (const float4*)F;   // row (b*768+c): 196 f4
    const float4* A4 = (const float4*)A;   // row (b*32+m): 196 f4

    // staging index precompute: F 96*14=1344 f4 (u=0..5, u5: t<64); A 32*14=448 (u=0..1, u1: t<192)
    int i0 = t;          int fc0 = i0 / 14, fq0 = i0 - fc0 * 14;
    int i1 = t + 256;    int fc1 = i1 / 14, fq1 = i1 - fc1 * 14;
    int i2 = t + 512;    int fc2 = i2 / 14, fq2 = i2 - fc2 * 14;
    int i3 = t + 768;    int fc3 = i3 / 14, fq3 = i3 - fc3 * 14;
    int i4 = t + 1024;   int fc4 = i4 / 14, fq4 = i4 - fc4 * 14;
    int i5 = t + 1280;   int fc5 = (t < 64) ? (i5 / 14) : 0, fq5 = (t < 64) ? (i5 - (i5 / 14) * 14) : 0;
    int a0i = t;         int ac0 = a0i / 14, aq0 = a0i - ac0 * 14;
    int a1i = t + 256;   int ac1 = (t < 192) ? (a1i / 14) : 0, aq1 = (t < 192) ? (a1i - (a1i / 14) * 14) : 0;

    size_t fb0 = (size_t)(b * CF + cbase + fc0) * 196 + fq0;
    size_t fb1 = (size_t)(b * CF + cbase + fc1) * 196 + fq1;
    size_t fb2 = (size_t)(b * CF + cbase + fc2) * 196 + fq2;
    size_t fb3 = (size_t)(b * CF + cbase + fc3) * 196 + fq3;
    size_t fb4 = (size_t)(b * CF + cbase + fc4) * 196 + fq4;
    size_t fb5 = (size_t)(b * CF + cbase + fc5) * 196 + fq5;
    size_t ab0 = (size_t)(b * 32 + ac0) * 196 + aq0;
    size_t ab1 = (size_t)(b * 32 + ac1) * 196 + aq1;

    float4 fr0, fr1, fr2, fr3, fr4, fr5, ar0, ar1;
    float acc[4][3];
    #pragma unroll
    for (int i = 0; i < 4; ++i)
        #pragma unroll
        for (int j = 0; j < 3; ++j) acc[i][j] = 0.f;

    // prologue: chunk 0
    fr0 = F4[fb0]; fr1 = F4[fb1]; fr2 = F4[fb2]; fr3 = F4[fb3]; fr4 = F4[fb4];
    if (t < 64) fr5 = F4[fb5];
    ar0 = A4[ab0];
    if (t < 192) ar1 = A4[ab1];
    Fs[0][fc0][fq0] = fr0; Fs[0][fc1][fq1] = fr1; Fs[0][fc2][fq2] = fr2;
    Fs[0][fc3][fq3] = fr3; Fs[0][fc4][fq4] = fr4;
    if (t < 64) Fs[0][fc5][fq5] = fr5;
    As[0][ac0][aq0] = ar0;
    if (t < 192) As[0][ac1][aq1] = ar1;

    for (int ch = 0; ch < 14; ++ch) {
        int buf = ch & 1;
        __syncthreads();
        if (ch + 1 < 14) {
            size_t off = (size_t)(ch + 1) * 14;
            fr0 = F4[fb0 + off]; fr1 = F4[fb1 + off]; fr2 = F4[fb2 + off];
            fr3 = F4[fb3 + off]; fr4 = F4[fb4 + off];
            if (t < 64) fr5 = F4[fb5 + off];
            ar0 = A4[ab0 + off];
            if (t < 192) ar1 = A4[ab1 + off];
        }
        #pragma unroll 2
        for (int q = 0; q < 14; ++q) {
            float4 a_0 = As[buf][m0 + 0][q];
            float4 a_1 = As[buf][m0 + 1][q];
            float4 a_2 = As[buf][m0 + 2][q];
            float4 a_3 = As[buf][m0 + 3][q];
            float4 f_0 = Fs[buf][c0 + 0][q];
            float4 f_1 = Fs[buf][c0 + 1][q];
            float4 f_2 = Fs[buf][c0 + 2][q];
            acc[0][0] = dot4(a_0, f_0, acc[0][0]); acc[0][1] = dot4(a_0, f_1, acc[0][1]); acc[0][2] = dot4(a_0, f_2, acc[0][2]);
            acc[1][0] = dot4(a_1, f_0, acc[1][0]); acc[1][1] = dot4(a_1, f_1, acc[1][1]); acc[1][2] = dot4(a_1, f_2, acc[1][2]);
            acc[2][0] = dot4(a_2, f_0, acc[2][0]); acc[2][1] = dot4(a_2, f_1, acc[2][1]); acc[2][2] = dot4(a_2, f_2, acc[2][2]);
            acc[3][0] = dot4(a_3, f_0, acc[3][0]); acc[3][1] = dot4(a_3, f_1, acc[3][1]); acc[3][2] = dot4(a_3, f_2, acc[3][2]);
        }
        if (ch + 1 < 14) {
            int nb = buf ^ 1;
            Fs[nb][fc0][fq0] = fr0; Fs[nb][fc1][fq1] = fr1; Fs[nb][fc2][fq2] = fr2;
            Fs[nb][fc3][fq3] = fr3; Fs[nb][fc4][fq4] = fr4;
            if (t < 64) Fs[nb][fc5][fq5] = fr5;
            As[nb][ac0][aq0] = ar0;
            if (t < 192) As[nb][ac1][aq1] = ar1;
        }
    }
    #pragma unroll
    for (int i = 0; i < 4; ++i)
        #pragma unroll
        for (int j = 0; j < 3; ++j)
            V[(size_t)(b * 32 + m0 + i) * 768 + cbase + c0 + j] = acc[i][j] * (1.f / 784.f);
}

// ================= kB1/kB2: C_new + rcloss
__global__ __launch_bounds__(256) void kB1(const float* __restrict__ V,
                                           const float* __restrict__ C,
                                           float* __restrict__ Cnew_out,
                                           float* __restrict__ partial) {
    int j = blockIdx.x * 256 + threadIdx.x;
    float c = C[j];
    float s = 0.f;
    for (int b = 0; b < 32; ++b) s += V[(size_t)b * MCF + j];
    float cn = c + BETA * (s * (1.f / 32.f) - c);
    Cnew_out[j] = cn;
    float ds = 0.f;
    for (int b = 0; b < 32; ++b) {
        float d = V[(size_t)b * MCF + j] - cn;
        ds = fmaf(d, d, ds);
    }
    __shared__ float red[256];
    red[threadIdx.x] = ds;
    __syncthreads();
    for (int off = 128; off > 0; off >>= 1) {
        if (threadIdx.x < off) red[threadIdx.x] += red[threadIdx.x + off];
        __syncthreads();
    }
    if (threadIdx.x == 0) partial[blockIdx.x] = red[0];
}

__global__ void kB2(const float* __restrict__ partial, float* __restrict__ out) {
    if (threadIdx.x == 0) {
        float s = 0.f;
        for (int i = 0; i < 96; ++i) s += partial[i];
        out[0] = s / (32.f * 24576.f);
    }
}

// ================= kC: Xpre[t][g][b][j] = X_t @ Wxg^T + bxg + bhg
__global__ __launch_bounds__(256) void kC(const float* __restrict__ V,
    const float* __restrict__ Wxi, const float* __restrict__ Wxf,
    const float* __restrict__ Wxo, const float* __restrict__ Wxc,
    const float* __restrict__ bxi, const float* __restrict__ bxf,
    const float* __restrict__ bxo, const float* __restrict__ bxc,
    const float* __restrict__ bhi, const float* __restrict__ bhf,
    const float* __restrict__ bho, const float* __restrict__ bhc,
    float* __restrict__ Xpre) {
    __shared__ float As_[64][17];
    __shared__ float Bs[64][17];
    int rbase = blockIdx.x * 64;
    int nbase = blockIdx.y * 64;
    int g = nbase >> 10;
    int jbase = nbase & 1023;
    const float* Wg  = (g == 0) ? Wxi : (g == 1) ? Wxf : (g == 2) ? Wxo : Wxc;
    const float* bxg = (g == 0) ? bxi : (g == 1) ? bxf : (g == 2) ? bxo : bxc;
    const float* bhg = (g == 0) ? bhi : (g == 1) ? bhf : (g == 2) ? bho : bhc;
    int t = threadIdx.x;
    int tx = t & 15, ty = t >> 4;
    float acc[4][4] = {};
    for (int k0 = 0; k0 < CF; k0 += 16) {
        __syncthreads();
        #pragma unroll
        for (int u = 0; u < 4; ++u) {
            int idx = t + u * 256;
            int row = idx >> 4, kl = idx & 15;
            int r = rbase + row;
            As_[row][kl] = V[(size_t)(r & 31) * MCF + (r >> 5) * CF + k0 + kl];
            Bs[row][kl] = Wg[(size_t)(jbase + row) * CF + k0 + kl];
        }
        __syncthreads();
        #pragma unroll
        for (int kk = 0; kk < 16; ++kk) {
            float a[4], bv[4];
            #pragma unroll
            for (int i = 0; i < 4; ++i) a[i] = As_[ty * 4 + i][kk];
            #pragma unroll
            for (int jj = 0; jj < 4; ++jj) bv[jj] = Bs[tx * 4 + jj][kk];
            #pragma unroll
            for (int i = 0; i < 4; ++i)
                #pragma unroll
                for (int jj = 0; jj < 4; ++jj)
                    acc[i][jj] = fmaf(a[i], bv[jj], acc[i][jj]);
        }
    }
    #pragma unroll
    for (int jj = 0; jj < 4; ++jj) {
        int c = tx * 4 + jj;
        float bias = bxg[jbase + c] + bhg[jbase + c];
        #pragma unroll
        for (int i = 0; i < 4; ++i) {
            int r = rbase + ty * 4 + i;
            int tt = r >> 5, bb = r & 31;
            Xpre[(((size_t)tt * 4 + g) * 32 + bb) * 1024 + jbase + c] = acc[i][jj] + bias;
        }
    }
}

// ================= kL: persistent cooperative LSTM, 256 blocks x 256 thr
// block bi owns j-cols [bi*4, bi*4+4) across all 4 gates, all 32 b; cell state in regs (t<128)
__device__ __forceinline__ float sigf(float x) { return 1.f / (1.f + __expf(-x)); }

__global__ __launch_bounds__(256) void kL(
    const float* __restrict__ Xpre,
    const float* __restrict__ Whi, const float* __restrict__ Whf,
    const float* __restrict__ Who, const float* __restrict__ Whc,
    unsigned short* __restrict__ Hbf, float* __restrict__ outH) {
    __shared__ float Hs[32][260];       // 33280 B, quarter of K staged fp32
    __shared__ float pbuf[4][32][4];    // 2 KB
    cg::grid_group grid = cg::this_grid();
    const int bi = blockIdx.x;
    const int jbase = bi * 4;
    const int t = threadIdx.x;
    const int g = t >> 6;
    const int b = (t >> 1) & 31;
    const int jp = t & 1;
    const float* Wg = (g == 0) ? Whi : (g == 1) ? Whf : (g == 2) ? Who : Whc;
    const float* W0 = Wg + (size_t)(jbase + 2 * jp) * 1024;
    const float* W1 = W0 + 1024;
    float creg = 0.f;

    for (int step = 0; step < 32; ++step) {
        const float* xp = Xpre + ((size_t)(step * 4 + g) * 32 + b) * 1024 + jbase + 2 * jp;
        float pre0 = xp[0];
        float pre1 = xp[1];
        if (step > 0) {
            grid.sync();
            #pragma unroll 1
            for (int quarter = 0; quarter < 4; ++quarter) {
                int kb = quarter * 256;
                __syncthreads();
                // stage 32 x 256 bf16 -> fp32 LDS; idx bits: [1:0]=grp-lo, [6:2]=row, [9:7]=grp-hi
                #pragma unroll
                for (int u = 0; u < 4; ++u) {
                    int idx = u * 256 + t;
                    int row = (idx >> 2) & 31;
                    int grp = (idx & 3) | ((idx >> 7) << 2);
                    uint4 pk = *(const uint4*)(Hbf + row * 1024 + kb + grp * 8);
                    float2* dst = (float2*)&Hs[row][grp * 8];
                    float2 f;
                    f.x = __uint_as_float(pk.x << 16); f.y = __uint_as_float(pk.x & 0xffff0000u); dst[0] = f;
                    f.x = __uint_as_float(pk.y << 16); f.y = __uint_as_float(pk.y & 0xffff0000u); dst[1] = f;
                    f.x = __uint_as_float(pk.z << 16); f.y = __uint_as_float(pk.z & 0xffff0000u); dst[2] = f;
                    f.x = __uint_as_float(pk.w << 16); f.y = __uint_as_float(pk.w & 0xffff0000u); dst[3] = f;
                }
                __syncthreads();
                const float* w0p = W0 + kb;
                const float* w1p = W1 + kb;
                #pragma unroll 8
                for (int k4 = 0; k4 < 64; ++k4) {
                    float4 h  = *(const float4*)&Hs[b][k4 * 4];
                    float4 w0 = *(const float4*)&w0p[k4 * 4];
                    float4 w1 = *(const float4*)&w1p[k4 * 4];
                    pre0 = dot4(h, w0, pre0);
                    pre1 = dot4(h, w1, pre1);
                }
            }
        }
        pbuf[g][b][2 * jp]     = pre0;
        pbuf[g][b][2 * jp + 1] = pre1;
        __syncthreads();
        if (t < 128) {
            int bb = t >> 2, jj = t & 3;
            float I  = sigf(pbuf[0][bb][jj]);
            float Fg = sigf(pbuf[1][bb][jj]);
            float O  = sigf(pbuf[2][bb][jj]);
            float Ct = tanhf(pbuf[3][bb][jj]);
            creg = fmaf(Fg, creg, I * Ct);
            float h = O * tanhf(creg);
            if (step < 31) {
                unsigned int bits = __float_as_uint(h);
                unsigned int r = (bits + 0x7fffu + ((bits >> 16) & 1u)) >> 16;  // RNE bf16
                Hbf[bb * 1024 + jbase + jj] = (unsigned short)r;
            } else {
                outH[bb * 1024 + jbase + jj] = h;
            }
        }
        __syncthreads();
    }
}

extern "C" void kernel_launch(void* const* d_in, const int* in_sizes, int n_in,
                              void* d_out, int out_size, void* d_ws, size_t ws_size,
                              hipStream_t stream) {
    const float* F   = (const float*)d_in[0];
    const float* A   = (const float*)d_in[1];
    const float* C   = (const float*)d_in[2];
    const float* Wxi = (const float*)d_in[3];
    const float* bxi = (const float*)d_in[4];
    const float* Whi = (const float*)d_in[5];
    const float* bhi = (const float*)d_in[6];
    const float* Wxf = (const float*)d_in[7];
    const float* bxf = (const float*)d_in[8];
    const float* Whf = (const float*)d_in[9];
    const float* bhf = (const float*)d_in[10];
    const float* Wxo = (const float*)d_in[11];
    const float* bxo = (const float*)d_in[12];
    const float* Who = (const float*)d_in[13];
    const float* bho = (const float*)d_in[14];
    const float* Wxc = (const float*)d_in[15];
    const float* bxc = (const float*)d_in[16];
    const float* Whc = (const float*)d_in[17];
    const float* bhc = (const float*)d_in[18];

    float* out   = (float*)d_out;
    float* outH  = out;           // 32768
    float* outRC = out + 32768;   // 1
    float* outC  = out + 32769;   // 24576

    float* ws   = (float*)d_ws;
    float* V    = ws;                          // 786432
    float* Xpre = ws + 786432;                 // 4194304
    unsigned short* Hbf = (unsigned short*)(ws + 786432 + 4194304);  // 32768 ushorts = 16384 floats
    float* part = ws + 786432 + 4194304 + 16384;                     // 96

    kA2<<<dim3(256), 256, 0, stream>>>(F, A, V);
    kB1<<<dim3(96), 256, 0, stream>>>(V, C, outC, part);
    kB2<<<1, 64, 0, stream>>>(part, outRC);
    kC<<<dim3(16, 64), 256, 0, stream>>>(V, Wxi, Wxf, Wxo, Wxc,
                                         bxi, bxf, bxo, bxc,
                                         bhi, bhf, bho, bhc, Xpre);

    void* args[] = { (void*)&Xpre, (void*)&Whi, (void*)&Whf, (void*)&Who, (void*)&Whc,
                     (void*)&Hbf, (void*)&outH };
    hipLaunchCooperativeKernel((const void*)kL, dim3(256), dim3(256), args, 0, stream);
}

// Round 3
// 1245.265 us; speedup vs baseline: 1.7142x; 1.7142x over previous
//
#include <hip/hip_runtime.h>
#include <hip/hip_cooperative_groups.h>
#include <math.h>

namespace cg = cooperative_groups;

#define CF 768
#define MM 32
#define HW 784
#define MCF 24576
#define BETA 0.05f

typedef __attribute__((ext_vector_type(8))) short bf16x8;
typedef __attribute__((ext_vector_type(4))) float f32x4;

__device__ __forceinline__ float dot4(float4 a, float4 b, float acc) {
    acc = fmaf(a.x, b.x, acc); acc = fmaf(a.y, b.y, acc);
    acc = fmaf(a.z, b.z, acc); acc = fmaf(a.w, b.w, acc);
    return acc;
}

__device__ __forceinline__ unsigned short bf16rne(float x) {
    unsigned int bits = __float_as_uint(x);
    unsigned int r = (bits + 0x7fffu + ((bits >> 16) & 1u)) >> 16;
    return (unsigned short)r;
}

__device__ __forceinline__ float sigf(float x) { return 1.f / (1.f + __expf(-x)); }

// ================= kA2: V[b][m][c] = (1/784) sum_hw A[b][m][hw] * F[b][c][hw]
#define KA_CT 96
#define KA_PAD 15

__global__ __launch_bounds__(256) void kA2(const float* __restrict__ F,
                                           const float* __restrict__ A,
                                           float* __restrict__ V) {
    __shared__ float4 Fs[2][KA_CT][KA_PAD];
    __shared__ float4 As[2][32][KA_PAD];
    const int b = blockIdx.x >> 3;
    const int cbase = (blockIdx.x & 7) * KA_CT;
    const int t = threadIdx.x;
    const int tx = t & 31;
    const int ty = t >> 5;
    const int c0 = tx * 3, m0 = ty * 4;
    const float4* F4 = (const float4*)F;
    const float4* A4 = (const float4*)A;

    int i0 = t;          int fc0 = i0 / 14, fq0 = i0 - fc0 * 14;
    int i1 = t + 256;    int fc1 = i1 / 14, fq1 = i1 - fc1 * 14;
    int i2 = t + 512;    int fc2 = i2 / 14, fq2 = i2 - fc2 * 14;
    int i3 = t + 768;    int fc3 = i3 / 14, fq3 = i3 - fc3 * 14;
    int i4 = t + 1024;   int fc4 = i4 / 14, fq4 = i4 - fc4 * 14;
    int i5 = t + 1280;   int fc5 = (t < 64) ? (i5 / 14) : 0, fq5 = (t < 64) ? (i5 - (i5 / 14) * 14) : 0;
    int a0i = t;         int ac0 = a0i / 14, aq0 = a0i - ac0 * 14;
    int a1i = t + 256;   int ac1 = (t < 192) ? (a1i / 14) : 0, aq1 = (t < 192) ? (a1i - (a1i / 14) * 14) : 0;

    size_t fb0 = (size_t)(b * CF + cbase + fc0) * 196 + fq0;
    size_t fb1 = (size_t)(b * CF + cbase + fc1) * 196 + fq1;
    size_t fb2 = (size_t)(b * CF + cbase + fc2) * 196 + fq2;
    size_t fb3 = (size_t)(b * CF + cbase + fc3) * 196 + fq3;
    size_t fb4 = (size_t)(b * CF + cbase + fc4) * 196 + fq4;
    size_t fb5 = (size_t)(b * CF + cbase + fc5) * 196 + fq5;
    size_t ab0 = (size_t)(b * 32 + ac0) * 196 + aq0;
    size_t ab1 = (size_t)(b * 32 + ac1) * 196 + aq1;

    float4 fr0, fr1, fr2, fr3, fr4, fr5, ar0, ar1;
    float acc[4][3];
    #pragma unroll
    for (int i = 0; i < 4; ++i)
        #pragma unroll
        for (int j = 0; j < 3; ++j) acc[i][j] = 0.f;

    fr0 = F4[fb0]; fr1 = F4[fb1]; fr2 = F4[fb2]; fr3 = F4[fb3]; fr4 = F4[fb4];
    if (t < 64) fr5 = F4[fb5];
    ar0 = A4[ab0];
    if (t < 192) ar1 = A4[ab1];
    Fs[0][fc0][fq0] = fr0; Fs[0][fc1][fq1] = fr1; Fs[0][fc2][fq2] = fr2;
    Fs[0][fc3][fq3] = fr3; Fs[0][fc4][fq4] = fr4;
    if (t < 64) Fs[0][fc5][fq5] = fr5;
    As[0][ac0][aq0] = ar0;
    if (t < 192) As[0][ac1][aq1] = ar1;

    for (int ch = 0; ch < 14; ++ch) {
        int buf = ch & 1;
        __syncthreads();
        if (ch + 1 < 14) {
            size_t off = (size_t)(ch + 1) * 14;
            fr0 = F4[fb0 + off]; fr1 = F4[fb1 + off]; fr2 = F4[fb2 + off];
            fr3 = F4[fb3 + off]; fr4 = F4[fb4 + off];
            if (t < 64) fr5 = F4[fb5 + off];
            ar0 = A4[ab0 + off];
            if (t < 192) ar1 = A4[ab1 + off];
        }
        #pragma unroll 2
        for (int q = 0; q < 14; ++q) {
            float4 a_0 = As[buf][m0 + 0][q];
            float4 a_1 = As[buf][m0 + 1][q];
            float4 a_2 = As[buf][m0 + 2][q];
            float4 a_3 = As[buf][m0 + 3][q];
            float4 f_0 = Fs[buf][c0 + 0][q];
            float4 f_1 = Fs[buf][c0 + 1][q];
            float4 f_2 = Fs[buf][c0 + 2][q];
            acc[0][0] = dot4(a_0, f_0, acc[0][0]); acc[0][1] = dot4(a_0, f_1, acc[0][1]); acc[0][2] = dot4(a_0, f_2, acc[0][2]);
            acc[1][0] = dot4(a_1, f_0, acc[1][0]); acc[1][1] = dot4(a_1, f_1, acc[1][1]); acc[1][2] = dot4(a_1, f_2, acc[1][2]);
            acc[2][0] = dot4(a_2, f_0, acc[2][0]); acc[2][1] = dot4(a_2, f_1, acc[2][1]); acc[2][2] = dot4(a_2, f_2, acc[2][2]);
            acc[3][0] = dot4(a_3, f_0, acc[3][0]); acc[3][1] = dot4(a_3, f_1, acc[3][1]); acc[3][2] = dot4(a_3, f_2, acc[3][2]);
        }
        if (ch + 1 < 14) {
            int nb = buf ^ 1;
            Fs[nb][fc0][fq0] = fr0; Fs[nb][fc1][fq1] = fr1; Fs[nb][fc2][fq2] = fr2;
            Fs[nb][fc3][fq3] = fr3; Fs[nb][fc4][fq4] = fr4;
            if (t < 64) Fs[nb][fc5][fq5] = fr5;
            As[nb][ac0][aq0] = ar0;
            if (t < 192) As[nb][ac1][aq1] = ar1;
        }
    }
    #pragma unroll
    for (int i = 0; i < 4; ++i)
        #pragma unroll
        for (int j = 0; j < 3; ++j)
            V[(size_t)(b * 32 + m0 + i) * 768 + cbase + c0 + j] = acc[i][j] * (1.f / 784.f);
}

// ================= kB1/kB2: C_new + rcloss
__global__ __launch_bounds__(256) void kB1(const float* __restrict__ V,
                                           const float* __restrict__ C,
                                           float* __restrict__ Cnew_out,
                                           float* __restrict__ partial) {
    int j = blockIdx.x * 256 + threadIdx.x;
    float c = C[j];
    float s = 0.f;
    for (int b = 0; b < 32; ++b) s += V[(size_t)b * MCF + j];
    float cn = c + BETA * (s * (1.f / 32.f) - c);
    Cnew_out[j] = cn;
    float ds = 0.f;
    for (int b = 0; b < 32; ++b) {
        float d = V[(size_t)b * MCF + j] - cn;
        ds = fmaf(d, d, ds);
    }
    __shared__ float red[256];
    red[threadIdx.x] = ds;
    __syncthreads();
    for (int off = 128; off > 0; off >>= 1) {
        if (threadIdx.x < off) red[threadIdx.x] += red[threadIdx.x + off];
        __syncthreads();
    }
    if (threadIdx.x == 0) partial[blockIdx.x] = red[0];
}

__global__ void kB2(const float* __restrict__ partial, float* __restrict__ out) {
    if (threadIdx.x == 0) {
        float s = 0.f;
        for (int i = 0; i < 96; ++i) s += partial[i];
        out[0] = s / (32.f * 24576.f);
    }
}

// ================= kC: Xpre[t][g][b][j] = X_t @ Wxg^T + bxg + bhg (fp32)
__global__ __launch_bounds__(256) void kC(const float* __restrict__ V,
    const float* __restrict__ Wxi, const float* __restrict__ Wxf,
    const float* __restrict__ Wxo, const float* __restrict__ Wxc,
    const float* __restrict__ bxi, const float* __restrict__ bxf,
    const float* __restrict__ bxo, const float* __restrict__ bxc,
    const float* __restrict__ bhi, const float* __restrict__ bhf,
    const float* __restrict__ bho, const float* __restrict__ bhc,
    float* __restrict__ Xpre) {
    __shared__ float As_[64][17];
    __shared__ float Bs[64][17];
    int rbase = blockIdx.x * 64;
    int nbase = blockIdx.y * 64;
    int g = nbase >> 10;
    int jbase = nbase & 1023;
    const float* Wg  = (g == 0) ? Wxi : (g == 1) ? Wxf : (g == 2) ? Wxo : Wxc;
    const float* bxg = (g == 0) ? bxi : (g == 1) ? bxf : (g == 2) ? bxo : bxc;
    const float* bhg = (g == 0) ? bhi : (g == 1) ? bhf : (g == 2) ? bho : bhc;
    int t = threadIdx.x;
    int tx = t & 15, ty = t >> 4;
    float acc[4][4] = {};
    for (int k0 = 0; k0 < CF; k0 += 16) {
        __syncthreads();
        #pragma unroll
        for (int u = 0; u < 4; ++u) {
            int idx = t + u * 256;
            int row = idx >> 4, kl = idx & 15;
            int r = rbase + row;
            As_[row][kl] = V[(size_t)(r & 31) * MCF + (r >> 5) * CF + k0 + kl];
            Bs[row][kl] = Wg[(size_t)(jbase + row) * CF + k0 + kl];
        }
        __syncthreads();
        #pragma unroll
        for (int kk = 0; kk < 16; ++kk) {
            float a[4], bv[4];
            #pragma unroll
            for (int i = 0; i < 4; ++i) a[i] = As_[ty * 4 + i][kk];
            #pragma unroll
            for (int jj = 0; jj < 4; ++jj) bv[jj] = Bs[tx * 4 + jj][kk];
            #pragma unroll
            for (int i = 0; i < 4; ++i)
                #pragma unroll
                for (int jj = 0; jj < 4; ++jj)
                    acc[i][jj] = fmaf(a[i], bv[jj], acc[i][jj]);
        }
    }
    #pragma unroll
    for (int jj = 0; jj < 4; ++jj) {
        int c = tx * 4 + jj;
        float bias = bxg[jbase + c] + bhg[jbase + c];
        #pragma unroll
        for (int i = 0; i < 4; ++i) {
            int r = rbase + ty * 4 + i;
            int tt = r >> 5, bb = r & 31;
            Xpre[(((size_t)tt * 4 + g) * 32 + bb) * 1024 + jbase + c] = acc[i][jj] + bias;
        }
    }
}

// ================= kL3: cooperative MFMA LSTM. 256 blocks x 512 thr (8 waves).
// Block bi owns j-cols [bi*4, bi*4+4) x 4 gates (16 W rows). W held in LDS in
// fragment order (bf16). Wave w owns K-eighth [w*128, w*128+128). Per step:
// 8 global bf16 H-fragment loads + 8 MFMA per wave, LDS partial combine,
// pointwise gates by t<128, bf16 H write to ping-pong buffer, grid.sync.
__global__ __launch_bounds__(512) void kL3(
    const float* __restrict__ Xpre,
    const float* __restrict__ Whi, const float* __restrict__ Whf,
    const float* __restrict__ Who, const float* __restrict__ Whc,
    unsigned short* __restrict__ Hbf, float* __restrict__ outH) {
    __shared__ unsigned short Wf[2048 * 8];   // 32 KB, fragment-ordered
    __shared__ float pbuf[8][32][17];         // 17.4 KB
    cg::grid_group grid = cg::this_grid();
    const int bi = blockIdx.x;
    const int jbase = bi * 4;
    const int t = threadIdx.x;
    const int lane = t & 63;
    const int w = t >> 6;            // wave 0..7
    const int n = lane & 15;         // MFMA col / A row
    const int j8 = lane >> 4;        // k-subgroup 0..3

    // ---- one-time: stage W slice into LDS in exact B-fragment order (bf16)
    #pragma unroll
    for (int it = 0; it < 4; ++it) {
        int c = it * 512 + t;        // 0..2047 chunks of 8 elems
        int cl = c & 63, cks = (c >> 6) & 3, cw = c >> 8;
        int cn = cl & 15, cj8 = cl >> 4;
        int g = cn >> 2, jj = cn & 3;
        int k = cw * 128 + cks * 32 + cj8 * 8;
        const float* Wg = (g == 0) ? Whi : (g == 1) ? Whf : (g == 2) ? Who : Whc;
        const float* src = Wg + (size_t)(jbase + jj) * 1024 + k;
        float4 f0 = *(const float4*)src;
        float4 f1 = *(const float4*)(src + 4);
        unsigned short u[8];
        u[0] = bf16rne(f0.x); u[1] = bf16rne(f0.y); u[2] = bf16rne(f0.z); u[3] = bf16rne(f0.w);
        u[4] = bf16rne(f1.x); u[5] = bf16rne(f1.y); u[6] = bf16rne(f1.z); u[7] = bf16rne(f1.w);
        *(uint4*)&Wf[c * 8] = *(const uint4*)u;
    }
    float creg = 0.f;
    __syncthreads();

    for (int step = 0; step < 32; ++step) {
        // Xpre loads (independent of H) — issue before the grid barrier
        float pre[4] = {0.f, 0.f, 0.f, 0.f};
        if (t < 128) {
            int b = t >> 2, jj = t & 3;
            #pragma unroll
            for (int g = 0; g < 4; ++g)
                pre[g] = Xpre[(((size_t)step * 4 + g) * 32 + b) * 1024 + jbase + jj];
        }
        if (step > 0) {
            grid.sync();   // H(step-1) writes globally visible
            const unsigned short* hb = Hbf + ((step - 1) & 1) * 32768;
            f32x4 acc0 = {0.f, 0.f, 0.f, 0.f};
            f32x4 acc1 = {0.f, 0.f, 0.f, 0.f};
            const int kw = w * 128;
            #pragma unroll
            for (int ks = 0; ks < 4; ++ks) {
                int k = kw + ks * 32 + j8 * 8;
                bf16x8 a0 = *(const bf16x8*)(hb + (size_t)n * 1024 + k);
                bf16x8 a1 = *(const bf16x8*)(hb + (size_t)(n + 16) * 1024 + k);
                bf16x8 bfr = *(const bf16x8*)&Wf[((w * 4 + ks) * 64 + lane) * 8];
                acc0 = __builtin_amdgcn_mfma_f32_16x16x32_bf16(a0, bfr, acc0, 0, 0, 0);
                acc1 = __builtin_amdgcn_mfma_f32_16x16x32_bf16(a1, bfr, acc1, 0, 0, 0);
            }
            #pragma unroll
            for (int r = 0; r < 4; ++r) {
                pbuf[w][j8 * 4 + r][n] = acc0[r];
                pbuf[w][16 + j8 * 4 + r][n] = acc1[r];
            }
        }
        __syncthreads();
        if (t < 128) {
            int b = t >> 2, jj = t & 3;
            if (step > 0) {
                #pragma unroll
                for (int g = 0; g < 4; ++g) {
                    float s = pre[g];
                    #pragma unroll
                    for (int w2 = 0; w2 < 8; ++w2) s += pbuf[w2][b][g * 4 + jj];
                    pre[g] = s;
                }
            }
            float I  = sigf(pre[0]);
            float Fg = sigf(pre[1]);
            float O  = sigf(pre[2]);
            float Ct = tanhf(pre[3]);
            creg = fmaf(Fg, creg, I * Ct);
            float h = O * tanhf(creg);
            if (step < 31) {
                unsigned short* hw_ = Hbf + (step & 1) * 32768;
                hw_[b * 1024 + jbase + jj] = bf16rne(h);
            } else {
                outH[b * 1024 + jbase + jj] = h;
            }
        }
        __syncthreads();
    }
}

extern "C" void kernel_launch(void* const* d_in, const int* in_sizes, int n_in,
                              void* d_out, int out_size, void* d_ws, size_t ws_size,
                              hipStream_t stream) {
    const float* F   = (const float*)d_in[0];
    const float* A   = (const float*)d_in[1];
    const float* C   = (const float*)d_in[2];
    const float* Wxi = (const float*)d_in[3];
    const float* bxi = (const float*)d_in[4];
    const float* Whi = (const float*)d_in[5];
    const float* bhi = (const float*)d_in[6];
    const float* Wxf = (const float*)d_in[7];
    const float* bxf = (const float*)d_in[8];
    const float* Whf = (const float*)d_in[9];
    const float* bhf = (const float*)d_in[10];
    const float* Wxo = (const float*)d_in[11];
    const float* bxo = (const float*)d_in[12];
    const float* Who = (const float*)d_in[13];
    const float* bho = (const float*)d_in[14];
    const float* Wxc = (const float*)d_in[15];
    const float* bxc = (const float*)d_in[16];
    const float* Whc = (const float*)d_in[17];
    const float* bhc = (const float*)d_in[18];

    float* out   = (float*)d_out;
    float* outH  = out;           // 32768
    float* outRC = out + 32768;   // 1
    float* outC  = out + 32769;   // 24576

    float* ws   = (float*)d_ws;
    float* V    = ws;                          // 786432 floats
    float* Xpre = ws + 786432;                 // 4194304 floats
    float* part = ws + 4980736;                // 96 floats
    unsigned short* Hbf = (unsigned short*)(ws + 4980832);  // 2 x 32768 ushorts

    kA2<<<dim3(256), 256, 0, stream>>>(F, A, V);
    kB1<<<dim3(96), 256, 0, stream>>>(V, C, outC, part);
    kB2<<<1, 64, 0, stream>>>(part, outRC);
    kC<<<dim3(16, 64), 256, 0, stream>>>(V, Wxi, Wxf, Wxo, Wxc,
                                         bxi, bxf, bxo, bxc,
                                         bhi, bhf, bho, bhc, Xpre);

    void* args[] = { (void*)&Xpre, (void*)&Whi, (void*)&Whf, (void*)&Who, (void*)&Whc,
                     (void*)&Hbf, (void*)&outH };
    hipLaunchCooperativeKernel((const void*)kL3, dim3(256), dim3(512), args, 0, stream);
}

// Round 4
// 381.507 us; speedup vs baseline: 5.5951x; 3.2641x over previous
//
#include <hip/hip_runtime.h>
#include <math.h>

#define CF 768
#define MM 32
#define HW 784
#define MCF 24576
#define BETA 0.05f

typedef __attribute__((ext_vector_type(8))) short bf16x8;
typedef __attribute__((ext_vector_type(4))) float f32x4;

__device__ __forceinline__ float dot4(float4 a, float4 b, float acc) {
    acc = fmaf(a.x, b.x, acc); acc = fmaf(a.y, b.y, acc);
    acc = fmaf(a.z, b.z, acc); acc = fmaf(a.w, b.w, acc);
    return acc;
}

__device__ __forceinline__ unsigned short bf16rne(float x) {
    unsigned int bits = __float_as_uint(x);
    unsigned int r = (bits + 0x7fffu + ((bits >> 16) & 1u)) >> 16;
    return (unsigned short)r;
}
__device__ __forceinline__ float bf2f(unsigned short u) {
    return __uint_as_float(((unsigned int)u) << 16);
}
__device__ __forceinline__ float sigf(float x) { return 1.f / (1.f + __expf(-x)); }

// ================= kA2: V[b][m][c] = (1/784) sum_hw A[b][m][hw] * F[b][c][hw]
#define KA_CT 96
#define KA_PAD 15

__global__ __launch_bounds__(256) void kA2(const float* __restrict__ F,
                                           const float* __restrict__ A,
                                           float* __restrict__ V) {
    __shared__ float4 Fs[2][KA_CT][KA_PAD];
    __shared__ float4 As[2][32][KA_PAD];
    const int b = blockIdx.x >> 3;
    const int cbase = (blockIdx.x & 7) * KA_CT;
    const int t = threadIdx.x;
    const int tx = t & 31;
    const int ty = t >> 5;
    const int c0 = tx * 3, m0 = ty * 4;
    const float4* F4 = (const float4*)F;
    const float4* A4 = (const float4*)A;

    int i0 = t;          int fc0 = i0 / 14, fq0 = i0 - fc0 * 14;
    int i1 = t + 256;    int fc1 = i1 / 14, fq1 = i1 - fc1 * 14;
    int i2 = t + 512;    int fc2 = i2 / 14, fq2 = i2 - fc2 * 14;
    int i3 = t + 768;    int fc3 = i3 / 14, fq3 = i3 - fc3 * 14;
    int i4 = t + 1024;   int fc4 = i4 / 14, fq4 = i4 - fc4 * 14;
    int i5 = t + 1280;   int fc5 = (t < 64) ? (i5 / 14) : 0, fq5 = (t < 64) ? (i5 - (i5 / 14) * 14) : 0;
    int a0i = t;         int ac0 = a0i / 14, aq0 = a0i - ac0 * 14;
    int a1i = t + 256;   int ac1 = (t < 192) ? (a1i / 14) : 0, aq1 = (t < 192) ? (a1i - (a1i / 14) * 14) : 0;

    size_t fb0 = (size_t)(b * CF + cbase + fc0) * 196 + fq0;
    size_t fb1 = (size_t)(b * CF + cbase + fc1) * 196 + fq1;
    size_t fb2 = (size_t)(b * CF + cbase + fc2) * 196 + fq2;
    size_t fb3 = (size_t)(b * CF + cbase + fc3) * 196 + fq3;
    size_t fb4 = (size_t)(b * CF + cbase + fc4) * 196 + fq4;
    size_t fb5 = (size_t)(b * CF + cbase + fc5) * 196 + fq5;
    size_t ab0 = (size_t)(b * 32 + ac0) * 196 + aq0;
    size_t ab1 = (size_t)(b * 32 + ac1) * 196 + aq1;

    float4 fr0, fr1, fr2, fr3, fr4, fr5, ar0, ar1;
    float acc[4][3];
    #pragma unroll
    for (int i = 0; i < 4; ++i)
        #pragma unroll
        for (int j = 0; j < 3; ++j) acc[i][j] = 0.f;

    fr0 = F4[fb0]; fr1 = F4[fb1]; fr2 = F4[fb2]; fr3 = F4[fb3]; fr4 = F4[fb4];
    if (t < 64) fr5 = F4[fb5];
    ar0 = A4[ab0];
    if (t < 192) ar1 = A4[ab1];
    Fs[0][fc0][fq0] = fr0; Fs[0][fc1][fq1] = fr1; Fs[0][fc2][fq2] = fr2;
    Fs[0][fc3][fq3] = fr3; Fs[0][fc4][fq4] = fr4;
    if (t < 64) Fs[0][fc5][fq5] = fr5;
    As[0][ac0][aq0] = ar0;
    if (t < 192) As[0][ac1][aq1] = ar1;

    for (int ch = 0; ch < 14; ++ch) {
        int buf = ch & 1;
        __syncthreads();
        if (ch + 1 < 14) {
            size_t off = (size_t)(ch + 1) * 14;
            fr0 = F4[fb0 + off]; fr1 = F4[fb1 + off]; fr2 = F4[fb2 + off];
            fr3 = F4[fb3 + off]; fr4 = F4[fb4 + off];
            if (t < 64) fr5 = F4[fb5 + off];
            ar0 = A4[ab0 + off];
            if (t < 192) ar1 = A4[ab1 + off];
        }
        #pragma unroll 2
        for (int q = 0; q < 14; ++q) {
            float4 a_0 = As[buf][m0 + 0][q];
            float4 a_1 = As[buf][m0 + 1][q];
            float4 a_2 = As[buf][m0 + 2][q];
            float4 a_3 = As[buf][m0 + 3][q];
            float4 f_0 = Fs[buf][c0 + 0][q];
            float4 f_1 = Fs[buf][c0 + 1][q];
            float4 f_2 = Fs[buf][c0 + 2][q];
            acc[0][0] = dot4(a_0, f_0, acc[0][0]); acc[0][1] = dot4(a_0, f_1, acc[0][1]); acc[0][2] = dot4(a_0, f_2, acc[0][2]);
            acc[1][0] = dot4(a_1, f_0, acc[1][0]); acc[1][1] = dot4(a_1, f_1, acc[1][1]); acc[1][2] = dot4(a_1, f_2, acc[1][2]);
            acc[2][0] = dot4(a_2, f_0, acc[2][0]); acc[2][1] = dot4(a_2, f_1, acc[2][1]); acc[2][2] = dot4(a_2, f_2, acc[2][2]);
            acc[3][0] = dot4(a_3, f_0, acc[3][0]); acc[3][1] = dot4(a_3, f_1, acc[3][1]); acc[3][2] = dot4(a_3, f_2, acc[3][2]);
        }
        if (ch + 1 < 14) {
            int nb = buf ^ 1;
            Fs[nb][fc0][fq0] = fr0; Fs[nb][fc1][fq1] = fr1; Fs[nb][fc2][fq2] = fr2;
            Fs[nb][fc3][fq3] = fr3; Fs[nb][fc4][fq4] = fr4;
            if (t < 64) Fs[nb][fc5][fq5] = fr5;
            As[nb][ac0][aq0] = ar0;
            if (t < 192) As[nb][ac1][aq1] = ar1;
        }
    }
    #pragma unroll
    for (int i = 0; i < 4; ++i)
        #pragma unroll
        for (int j = 0; j < 3; ++j)
            V[(size_t)(b * 32 + m0 + i) * 768 + cbase + c0 + j] = acc[i][j] * (1.f / 784.f);
}

// ================= kB1/kB2: C_new + rcloss
__global__ __launch_bounds__(256) void kB1(const float* __restrict__ V,
                                           const float* __restrict__ C,
                                           float* __restrict__ Cnew_out,
                                           float* __restrict__ partial) {
    int j = blockIdx.x * 256 + threadIdx.x;
    float c = C[j];
    float s = 0.f;
    for (int b = 0; b < 32; ++b) s += V[(size_t)b * MCF + j];
    float cn = c + BETA * (s * (1.f / 32.f) - c);
    Cnew_out[j] = cn;
    float ds = 0.f;
    for (int b = 0; b < 32; ++b) {
        float d = V[(size_t)b * MCF + j] - cn;
        ds = fmaf(d, d, ds);
    }
    __shared__ float red[256];
    red[threadIdx.x] = ds;
    __syncthreads();
    for (int off = 128; off > 0; off >>= 1) {
        if (threadIdx.x < off) red[threadIdx.x] += red[threadIdx.x + off];
        __syncthreads();
    }
    if (threadIdx.x == 0) partial[blockIdx.x] = red[0];
}

__global__ void kB2(const float* __restrict__ partial, float* __restrict__ out) {
    if (threadIdx.x == 0) {
        float s = 0.f;
        for (int i = 0; i < 96; ++i) s += partial[i];
        out[0] = s / (32.f * 24576.f);
    }
}

// ================= kC: Xpre_bf[t][g][b][j] = bf16(X_t @ Wxg^T + bxg + bhg)
__global__ __launch_bounds__(256) void kC(const float* __restrict__ V,
    const float* __restrict__ Wxi, const float* __restrict__ Wxf,
    const float* __restrict__ Wxo, const float* __restrict__ Wxc,
    const float* __restrict__ bxi, const float* __restrict__ bxf,
    const float* __restrict__ bxo, const float* __restrict__ bxc,
    const float* __restrict__ bhi, const float* __restrict__ bhf,
    const float* __restrict__ bho, const float* __restrict__ bhc,
    unsigned short* __restrict__ Xbf) {
    __shared__ float As_[64][17];
    __shared__ float Bs[64][17];
    int rbase = blockIdx.x * 64;
    int nbase = blockIdx.y * 64;
    int g = nbase >> 10;
    int jbase = nbase & 1023;
    const float* Wg  = (g == 0) ? Wxi : (g == 1) ? Wxf : (g == 2) ? Wxo : Wxc;
    const float* bxg = (g == 0) ? bxi : (g == 1) ? bxf : (g == 2) ? bxo : bxc;
    const float* bhg = (g == 0) ? bhi : (g == 1) ? bhf : (g == 2) ? bho : bhc;
    int t = threadIdx.x;
    int tx = t & 15, ty = t >> 4;
    float acc[4][4] = {};
    for (int k0 = 0; k0 < CF; k0 += 16) {
        __syncthreads();
        #pragma unroll
        for (int u = 0; u < 4; ++u) {
            int idx = t + u * 256;
            int row = idx >> 4, kl = idx & 15;
            int r = rbase + row;
            As_[row][kl] = V[(size_t)(r & 31) * MCF + (r >> 5) * CF + k0 + kl];
            Bs[row][kl] = Wg[(size_t)(jbase + row) * CF + k0 + kl];
        }
        __syncthreads();
        #pragma unroll
        for (int kk = 0; kk < 16; ++kk) {
            float a[4], bv[4];
            #pragma unroll
            for (int i = 0; i < 4; ++i) a[i] = As_[ty * 4 + i][kk];
            #pragma unroll
            for (int jj = 0; jj < 4; ++jj) bv[jj] = Bs[tx * 4 + jj][kk];
            #pragma unroll
            for (int i = 0; i < 4; ++i)
                #pragma unroll
                for (int jj = 0; jj < 4; ++jj)
                    acc[i][jj] = fmaf(a[i], bv[jj], acc[i][jj]);
        }
    }
    #pragma unroll
    for (int i = 0; i < 4; ++i) {
        int r = rbase + ty * 4 + i;
        int tt = r >> 5, bb = r & 31;
        unsigned short u4[4];
        #pragma unroll
        for (int jj = 0; jj < 4; ++jj) {
            int c = tx * 4 + jj;
            float bias = bxg[jbase + c] + bhg[jbase + c];
            u4[jj] = bf16rne(acc[i][jj] + bias);
        }
        *(ushort4*)&Xbf[(((size_t)tt * 4 + g) * 32 + bb) * 1024 + jbase + tx * 4] =
            *(const ushort4*)u4;
    }
}

// ================= kPrep: Wbf[g*1024+j][k] = bf16(Whg[j][k]); 2048 blocks x 256
__global__ __launch_bounds__(256) void kPrep(
    const float* __restrict__ Whi, const float* __restrict__ Whf,
    const float* __restrict__ Who, const float* __restrict__ Whc,
    unsigned short* __restrict__ Wbf) {
    size_t tid8 = ((size_t)blockIdx.x * 256 + threadIdx.x) * 8;
    int row = (int)(tid8 >> 10);
    int k = (int)(tid8 & 1023);
    int g = row >> 10, j = row & 1023;
    const float* Wg = (g == 0) ? Whi : (g == 1) ? Whf : (g == 2) ? Who : Whc;
    const float* src = Wg + (size_t)j * 1024 + k;
    float4 f0 = *(const float4*)src;
    float4 f1 = *(const float4*)(src + 4);
    unsigned short u[8];
    u[0] = bf16rne(f0.x); u[1] = bf16rne(f0.y); u[2] = bf16rne(f0.z); u[3] = bf16rne(f0.w);
    u[4] = bf16rne(f1.x); u[5] = bf16rne(f1.y); u[6] = bf16rne(f1.z); u[7] = bf16rne(f1.w);
    *(uint4*)&Wbf[tid8] = *(const uint4*)u;
}

// ================= kStep: one LSTM step. 256 blocks x 512 thr (8 waves).
// Block bi owns j-cols [bi*4, bi*4+4) x 4 gates (16 W rows, one MFMA n-tile).
// Wave w: K-eighth. n = g*4+jj. Hprev/Hnext ping-pong (bf16), Cst fp32 global.
__global__ __launch_bounds__(512) void kStep(
    const unsigned short* __restrict__ Wbf,
    const unsigned short* __restrict__ Xbf,
    const unsigned short* __restrict__ Hprev,
    unsigned short* __restrict__ Hnext,
    float* __restrict__ Cst,
    float* __restrict__ outH,
    int step) {
    __shared__ float pbuf[8][32][17];
    __shared__ float sbuf[32][17];
    const int bi = blockIdx.x;
    const int jbase = bi * 4;
    const int t = threadIdx.x;
    const int lane = t & 63;
    const int w = t >> 6;
    const int n = lane & 15;
    const int q = lane >> 4;

    if (step > 0) {
        const int g = n >> 2, jj = n & 3;
        const unsigned short* Wrow = Wbf + ((size_t)(g * 1024 + jbase + jj)) * 1024 + w * 128;
        const unsigned short* hb0 = Hprev + (size_t)n * 1024 + w * 128;
        const unsigned short* hb1 = Hprev + (size_t)(n + 16) * 1024 + w * 128;
        f32x4 acc0 = {0.f, 0.f, 0.f, 0.f};
        f32x4 acc1 = {0.f, 0.f, 0.f, 0.f};
        #pragma unroll
        for (int ks = 0; ks < 4; ++ks) {
            int k = ks * 32 + q * 8;
            bf16x8 bfrag = *(const bf16x8*)(Wrow + k);
            bf16x8 a0 = *(const bf16x8*)(hb0 + k);
            bf16x8 a1 = *(const bf16x8*)(hb1 + k);
            acc0 = __builtin_amdgcn_mfma_f32_16x16x32_bf16(a0, bfrag, acc0, 0, 0, 0);
            acc1 = __builtin_amdgcn_mfma_f32_16x16x32_bf16(a1, bfrag, acc1, 0, 0, 0);
        }
        #pragma unroll
        for (int r = 0; r < 4; ++r) {
            pbuf[w][q * 4 + r][n] = acc0[r];
            pbuf[w][16 + q * 4 + r][n] = acc1[r];
        }
    }
    __syncthreads();
    // phase 1: combine partials + Xpre -> sbuf[b][n]
    {
        int b = t >> 4, nn = t & 15;
        int g = nn >> 2, jj = nn & 3;
        float s = bf2f(Xbf[(((size_t)step * 4 + g) * 32 + b) * 1024 + jbase + jj]);
        if (step > 0) {
            #pragma unroll
            for (int w2 = 0; w2 < 8; ++w2) s += pbuf[w2][b][nn];
        }
        sbuf[b][nn] = s;
    }
    __syncthreads();
    // phase 2: gates + cell update + H write
    if (t < 128) {
        int b = t >> 2, jj = t & 3;
        float I  = sigf(sbuf[b][jj]);
        float Fg = sigf(sbuf[b][4 + jj]);
        float O  = sigf(sbuf[b][8 + jj]);
        float Ct = tanhf(sbuf[b][12 + jj]);
        float cprev = (step > 0) ? Cst[b * 1024 + jbase + jj] : 0.f;
        float c = fmaf(Fg, cprev, I * Ct);
        Cst[b * 1024 + jbase + jj] = c;
        float h = O * tanhf(c);
        if (step < 31) {
            Hnext[b * 1024 + jbase + jj] = bf16rne(h);
        } else {
            outH[b * 1024 + jbase + jj] = h;
        }
    }
}

extern "C" void kernel_launch(void* const* d_in, const int* in_sizes, int n_in,
                              void* d_out, int out_size, void* d_ws, size_t ws_size,
                              hipStream_t stream) {
    const float* F   = (const float*)d_in[0];
    const float* A   = (const float*)d_in[1];
    const float* C   = (const float*)d_in[2];
    const float* Wxi = (const float*)d_in[3];
    const float* bxi = (const float*)d_in[4];
    const float* Whi = (const float*)d_in[5];
    const float* bhi = (const float*)d_in[6];
    const float* Wxf = (const float*)d_in[7];
    const float* bxf = (const float*)d_in[8];
    const float* Whf = (const float*)d_in[9];
    const float* bhf = (const float*)d_in[10];
    const float* Wxo = (const float*)d_in[11];
    const float* bxo = (const float*)d_in[12];
    const float* Who = (const float*)d_in[13];
    const float* bho = (const float*)d_in[14];
    const float* Wxc = (const float*)d_in[15];
    const float* bxc = (const float*)d_in[16];
    const float* Whc = (const float*)d_in[17];
    const float* bhc = (const float*)d_in[18];

    float* out   = (float*)d_out;
    float* outH  = out;           // 32768
    float* outRC = out + 32768;   // 1
    float* outC  = out + 32769;   // 24576

    // ws layout (floats): Xbf [0,2097152) | Wbf [2097152,4194304) |
    // V [4194304,4980736) | part [4980736,4980832) | Hbf0/1 [4980832,5013600) |
    // Cst [5013600,5046368)   total ~20.2 MB
    float* ws = (float*)d_ws;
    unsigned short* Xbf = (unsigned short*)ws;                       // 4194304 us
    unsigned short* Wbf = (unsigned short*)(ws + 2097152);           // 4194304 us
    float* V    = ws + 4194304;                                      // 786432
    float* part = ws + 4980736;                                      // 96
    unsigned short* Hbf = (unsigned short*)(ws + 4980832);           // 2 x 32768 us
    float* Cst  = ws + 5013600;                                      // 32768

    kA2<<<dim3(256), 256, 0, stream>>>(F, A, V);
    kB1<<<dim3(96), 256, 0, stream>>>(V, C, outC, part);
    kB2<<<1, 64, 0, stream>>>(part, outRC);
    kC<<<dim3(16, 64), 256, 0, stream>>>(V, Wxi, Wxf, Wxo, Wxc,
                                         bxi, bxf, bxo, bxc,
                                         bhi, bhf, bho, bhc, Xbf);
    kPrep<<<dim3(2048), 256, 0, stream>>>(Whi, Whf, Who, Whc, Wbf);

    for (int step = 0; step < 32; ++step) {
        const unsigned short* Hprev = Hbf + ((step + 1) & 1) * 32768;
        unsigned short* Hnext = (unsigned short*)(Hbf + (step & 1) * 32768);
        kStep<<<dim3(256), 512, 0, stream>>>(Wbf, Xbf, Hprev, Hnext, Cst, outH, step);
    }
}

// Round 5
// 265.043 us; speedup vs baseline: 8.0537x; 1.4394x over previous
//
#include <hip/hip_runtime.h>
#include <math.h>

#define CF 768
#define MM 32
#define HW 784
#define MCF 24576
#define BETA 0.05f

typedef __attribute__((ext_vector_type(8))) short bf16x8;
typedef __attribute__((ext_vector_type(4))) float f32x4;

__device__ __forceinline__ float dot4(float4 a, float4 b, float acc) {
    acc = fmaf(a.x, b.x, acc); acc = fmaf(a.y, b.y, acc);
    acc = fmaf(a.z, b.z, acc); acc = fmaf(a.w, b.w, acc);
    return acc;
}

__device__ __forceinline__ unsigned short bf16rne(float x) {
    unsigned int bits = __float_as_uint(x);
    unsigned int r = (bits + 0x7fffu + ((bits >> 16) & 1u)) >> 16;
    return (unsigned short)r;
}
__device__ __forceinline__ float bf2f(unsigned short u) {
    return __uint_as_float(((unsigned int)u) << 16);
}
__device__ __forceinline__ float sigf(float x) { return 1.f / (1.f + __expf(-x)); }

// ================= kA2: Vbf[b][m][c] = bf16((1/784) sum_hw A[b][m][hw] * F[b][c][hw])
#define KA_CT 96
#define KA_PAD 15

__global__ __launch_bounds__(256) void kA2(const float* __restrict__ F,
                                           const float* __restrict__ A,
                                           unsigned short* __restrict__ Vbf) {
    __shared__ float4 Fs[2][KA_CT][KA_PAD];
    __shared__ float4 As[2][32][KA_PAD];
    const int b = blockIdx.x >> 3;
    const int cbase = (blockIdx.x & 7) * KA_CT;
    const int t = threadIdx.x;
    const int tx = t & 31;
    const int ty = t >> 5;
    const int c0 = tx * 3, m0 = ty * 4;
    const float4* F4 = (const float4*)F;
    const float4* A4 = (const float4*)A;

    int i0 = t;          int fc0 = i0 / 14, fq0 = i0 - fc0 * 14;
    int i1 = t + 256;    int fc1 = i1 / 14, fq1 = i1 - fc1 * 14;
    int i2 = t + 512;    int fc2 = i2 / 14, fq2 = i2 - fc2 * 14;
    int i3 = t + 768;    int fc3 = i3 / 14, fq3 = i3 - fc3 * 14;
    int i4 = t + 1024;   int fc4 = i4 / 14, fq4 = i4 - fc4 * 14;
    int i5 = t + 1280;   int fc5 = (t < 64) ? (i5 / 14) : 0, fq5 = (t < 64) ? (i5 - (i5 / 14) * 14) : 0;
    int a0i = t;         int ac0 = a0i / 14, aq0 = a0i - ac0 * 14;
    int a1i = t + 256;   int ac1 = (t < 192) ? (a1i / 14) : 0, aq1 = (t < 192) ? (a1i - (a1i / 14) * 14) : 0;

    size_t fb0 = (size_t)(b * CF + cbase + fc0) * 196 + fq0;
    size_t fb1 = (size_t)(b * CF + cbase + fc1) * 196 + fq1;
    size_t fb2 = (size_t)(b * CF + cbase + fc2) * 196 + fq2;
    size_t fb3 = (size_t)(b * CF + cbase + fc3) * 196 + fq3;
    size_t fb4 = (size_t)(b * CF + cbase + fc4) * 196 + fq4;
    size_t fb5 = (size_t)(b * CF + cbase + fc5) * 196 + fq5;
    size_t ab0 = (size_t)(b * 32 + ac0) * 196 + aq0;
    size_t ab1 = (size_t)(b * 32 + ac1) * 196 + aq1;

    float4 fr0, fr1, fr2, fr3, fr4, fr5, ar0, ar1;
    float acc[4][3];
    #pragma unroll
    for (int i = 0; i < 4; ++i)
        #pragma unroll
        for (int j = 0; j < 3; ++j) acc[i][j] = 0.f;

    fr0 = F4[fb0]; fr1 = F4[fb1]; fr2 = F4[fb2]; fr3 = F4[fb3]; fr4 = F4[fb4];
    if (t < 64) fr5 = F4[fb5];
    ar0 = A4[ab0];
    if (t < 192) ar1 = A4[ab1];
    Fs[0][fc0][fq0] = fr0; Fs[0][fc1][fq1] = fr1; Fs[0][fc2][fq2] = fr2;
    Fs[0][fc3][fq3] = fr3; Fs[0][fc4][fq4] = fr4;
    if (t < 64) Fs[0][fc5][fq5] = fr5;
    As[0][ac0][aq0] = ar0;
    if (t < 192) As[0][ac1][aq1] = ar1;

    for (int ch = 0; ch < 14; ++ch) {
        int buf = ch & 1;
        __syncthreads();
        if (ch + 1 < 14) {
            size_t off = (size_t)(ch + 1) * 14;
            fr0 = F4[fb0 + off]; fr1 = F4[fb1 + off]; fr2 = F4[fb2 + off];
            fr3 = F4[fb3 + off]; fr4 = F4[fb4 + off];
            if (t < 64) fr5 = F4[fb5 + off];
            ar0 = A4[ab0 + off];
            if (t < 192) ar1 = A4[ab1 + off];
        }
        #pragma unroll 2
        for (int q = 0; q < 14; ++q) {
            float4 a_0 = As[buf][m0 + 0][q];
            float4 a_1 = As[buf][m0 + 1][q];
            float4 a_2 = As[buf][m0 + 2][q];
            float4 a_3 = As[buf][m0 + 3][q];
            float4 f_0 = Fs[buf][c0 + 0][q];
            float4 f_1 = Fs[buf][c0 + 1][q];
            float4 f_2 = Fs[buf][c0 + 2][q];
            acc[0][0] = dot4(a_0, f_0, acc[0][0]); acc[0][1] = dot4(a_0, f_1, acc[0][1]); acc[0][2] = dot4(a_0, f_2, acc[0][2]);
            acc[1][0] = dot4(a_1, f_0, acc[1][0]); acc[1][1] = dot4(a_1, f_1, acc[1][1]); acc[1][2] = dot4(a_1, f_2, acc[1][2]);
            acc[2][0] = dot4(a_2, f_0, acc[2][0]); acc[2][1] = dot4(a_2, f_1, acc[2][1]); acc[2][2] = dot4(a_2, f_2, acc[2][2]);
            acc[3][0] = dot4(a_3, f_0, acc[3][0]); acc[3][1] = dot4(a_3, f_1, acc[3][1]); acc[3][2] = dot4(a_3, f_2, acc[3][2]);
        }
        if (ch + 1 < 14) {
            int nb = buf ^ 1;
            Fs[nb][fc0][fq0] = fr0; Fs[nb][fc1][fq1] = fr1; Fs[nb][fc2][fq2] = fr2;
            Fs[nb][fc3][fq3] = fr3; Fs[nb][fc4][fq4] = fr4;
            if (t < 64) Fs[nb][fc5][fq5] = fr5;
            As[nb][ac0][aq0] = ar0;
            if (t < 192) As[nb][ac1][aq1] = ar1;
        }
    }
    #pragma unroll
    for (int i = 0; i < 4; ++i)
        #pragma unroll
        for (int j = 0; j < 3; ++j)
            Vbf[(size_t)(b * 32 + m0 + i) * 768 + cbase + c0 + j] =
                bf16rne(acc[i][j] * (1.f / 784.f));
}

// ================= kB1/kB2: C_new + rcloss (reads bf16 V)
__global__ __launch_bounds__(256) void kB1(const unsigned short* __restrict__ Vbf,
                                           const float* __restrict__ C,
                                           float* __restrict__ Cnew_out,
                                           float* __restrict__ partial) {
    int j = blockIdx.x * 256 + threadIdx.x;
    float c = C[j];
    float s = 0.f;
    for (int b = 0; b < 32; ++b) s += bf2f(Vbf[(size_t)b * MCF + j]);
    float cn = c + BETA * (s * (1.f / 32.f) - c);
    Cnew_out[j] = cn;
    float ds = 0.f;
    for (int b = 0; b < 32; ++b) {
        float d = bf2f(Vbf[(size_t)b * MCF + j]) - cn;
        ds = fmaf(d, d, ds);
    }
    __shared__ float red[256];
    red[threadIdx.x] = ds;
    __syncthreads();
    for (int off = 128; off > 0; off >>= 1) {
        if (threadIdx.x < off) red[threadIdx.x] += red[threadIdx.x + off];
        __syncthreads();
    }
    if (threadIdx.x == 0) partial[blockIdx.x] = red[0];
}

__global__ void kB2(const float* __restrict__ partial, float* __restrict__ out) {
    if (threadIdx.x == 0) {
        float s = 0.f;
        for (int i = 0; i < 96; ++i) s += partial[i];
        out[0] = s / (32.f * 24576.f);
    }
}

// ================= kPrepX: Wxbf[g*1024+j][k] = bf16(Wxg[j][k]); rows 4096 x 768
__global__ __launch_bounds__(256) void kPrepX(
    const float* __restrict__ Wxi, const float* __restrict__ Wxf,
    const float* __restrict__ Wxo, const float* __restrict__ Wxc,
    unsigned short* __restrict__ Wxbf) {
    int gid = blockIdx.x * 256 + threadIdx.x;   // 393216 threads
    int row = gid / 96;
    int kq = (gid - row * 96) * 8;
    int g = row >> 10, j = row & 1023;
    const float* Wg = (g == 0) ? Wxi : (g == 1) ? Wxf : (g == 2) ? Wxo : Wxc;
    const float* src = Wg + (size_t)j * CF + kq;
    float4 f0 = *(const float4*)src;
    float4 f1 = *(const float4*)(src + 4);
    unsigned short u[8];
    u[0] = bf16rne(f0.x); u[1] = bf16rne(f0.y); u[2] = bf16rne(f0.z); u[3] = bf16rne(f0.w);
    u[4] = bf16rne(f1.x); u[5] = bf16rne(f1.y); u[6] = bf16rne(f1.z); u[7] = bf16rne(f1.w);
    *(uint4*)&Wxbf[(size_t)row * CF + kq] = *(const uint4*)u;
}

// ================= kC3: MFMA GEMM  Xbf = bf16( Vt[1024x768] @ Wx^T[768x4096] + bias )
// grid (16,32), 512 thr (8 waves). Rows r = t*32+b -> Vbf row (r&31)*32+(r>>5).
// A staged in LDS fragment-order (lane-linear slots, conflict-free both sides).
__global__ __launch_bounds__(512) void kC3(
    const unsigned short* __restrict__ Vbf,
    const unsigned short* __restrict__ Wxbf,
    const float* __restrict__ bxi, const float* __restrict__ bxf,
    const float* __restrict__ bxo, const float* __restrict__ bxc,
    const float* __restrict__ bhi, const float* __restrict__ bhf,
    const float* __restrict__ bho, const float* __restrict__ bhc,
    unsigned short* __restrict__ Xbf) {
    __shared__ unsigned short Asg[512 * 8];   // 8 KB, one 64-k chunk of the 64-row A tile
    const int bx = blockIdx.x;                // M-tile (64 rows)
    const int by = blockIdx.y;                // N-tile (128 cols)
    const int t = threadIdx.x;
    const int lane = t & 63;
    const int w = t >> 6;
    const int n = lane & 15;
    const int q = lane >> 4;
    const int mbase = bx * 64;

    // staging decode: slot16 = t -> p=w>>2, g=w&3, q_s=q, n_s=n
    const int st_row = (w & 3) * 16 + n;
    const int st_kb  = (w >> 2) * 4 + q;
    const int st_rg  = mbase + st_row;
    const int st_vrow = (st_rg & 31) * 32 + (st_rg >> 5);
    const unsigned short* st_src = Vbf + (size_t)st_vrow * CF + st_kb * 8;

    // B pointer: col = by*128 + w*16 + n -> Wxbf row (nb+n)
    const int nb = by * 128 + w * 16;
    const unsigned short* Brow = Wxbf + (size_t)(nb + n) * CF + q * 8;

    f32x4 acc[4];
    #pragma unroll
    for (int g = 0; g < 4; ++g) acc[g] = (f32x4){0.f, 0.f, 0.f, 0.f};

    uint4 st = *(const uint4*)st_src;
    for (int kc = 0; kc < 12; ++kc) {
        __syncthreads();
        *(uint4*)&Asg[t * 8] = st;
        __syncthreads();
        if (kc + 1 < 12) st = *(const uint4*)(st_src + (kc + 1) * 64);
        #pragma unroll
        for (int p = 0; p < 2; ++p) {
            bf16x8 bfr = *(const bf16x8*)(Brow + kc * 64 + p * 32);
            #pragma unroll
            for (int g = 0; g < 4; ++g) {
                bf16x8 a = *(const bf16x8*)&Asg[((p * 4 + g) * 64 + lane) * 8];
                acc[g] = __builtin_amdgcn_mfma_f32_16x16x32_bf16(a, bfr, acc[g], 0, 0, 0);
            }
        }
    }

    // epilogue: bias + bf16 store. gate uniform per block: gg = by>>3
    const int gg = by >> 3;
    const int j = (by & 7) * 128 + w * 16 + n;
    const float* bx_ = (gg == 0) ? bxi : (gg == 1) ? bxf : (gg == 2) ? bxo : bxc;
    const float* bh_ = (gg == 0) ? bhi : (gg == 1) ? bhf : (gg == 2) ? bho : bhc;
    const float bias = bx_[j] + bh_[j];
    #pragma unroll
    for (int g = 0; g < 4; ++g) {
        #pragma unroll
        for (int rr = 0; rr < 4; ++rr) {
            int rg = mbase + g * 16 + q * 4 + rr;
            int tt = rg >> 5, bb = rg & 31;
            Xbf[((size_t)(tt * 4 + gg) * 32 + bb) * 1024 + j] = bf16rne(acc[g][rr] + bias);
        }
    }
}

// ================= kPrep: Wbf[g*1024+j][k] = bf16(Whg[j][k]); 2048 blocks x 256
__global__ __launch_bounds__(256) void kPrep(
    const float* __restrict__ Whi, const float* __restrict__ Whf,
    const float* __restrict__ Who, const float* __restrict__ Whc,
    unsigned short* __restrict__ Wbf) {
    size_t tid8 = ((size_t)blockIdx.x * 256 + threadIdx.x) * 8;
    int row = (int)(tid8 >> 10);
    int k = (int)(tid8 & 1023);
    int g = row >> 10, j = row & 1023;
    const float* Wg = (g == 0) ? Whi : (g == 1) ? Whf : (g == 2) ? Who : Whc;
    const float* src = Wg + (size_t)j * 1024 + k;
    float4 f0 = *(const float4*)src;
    float4 f1 = *(const float4*)(src + 4);
    unsigned short u[8];
    u[0] = bf16rne(f0.x); u[1] = bf16rne(f0.y); u[2] = bf16rne(f0.z); u[3] = bf16rne(f0.w);
    u[4] = bf16rne(f1.x); u[5] = bf16rne(f1.y); u[6] = bf16rne(f1.z); u[7] = bf16rne(f1.w);
    *(uint4*)&Wbf[tid8] = *(const uint4*)u;
}

// ================= kStep: one LSTM step. 256 blocks x 512 thr (8 waves).
__global__ __launch_bounds__(512) void kStep(
    const unsigned short* __restrict__ Wbf,
    const unsigned short* __restrict__ Xbf,
    const unsigned short* __restrict__ Hprev,
    unsigned short* __restrict__ Hnext,
    float* __restrict__ Cst,
    float* __restrict__ outH,
    int step) {
    __shared__ float pbuf[8][32][17];
    __shared__ float sbuf[32][17];
    const int bi = blockIdx.x;
    const int jbase = bi * 4;
    const int t = threadIdx.x;
    const int lane = t & 63;
    const int w = t >> 6;
    const int n = lane & 15;
    const int q = lane >> 4;

    if (step > 0) {
        const int g = n >> 2, jj = n & 3;
        const unsigned short* Wrow = Wbf + ((size_t)(g * 1024 + jbase + jj)) * 1024 + w * 128;
        const unsigned short* hb0 = Hprev + (size_t)n * 1024 + w * 128;
        const unsigned short* hb1 = Hprev + (size_t)(n + 16) * 1024 + w * 128;
        f32x4 acc0 = {0.f, 0.f, 0.f, 0.f};
        f32x4 acc1 = {0.f, 0.f, 0.f, 0.f};
        #pragma unroll
        for (int ks = 0; ks < 4; ++ks) {
            int k = ks * 32 + q * 8;
            bf16x8 bfrag = *(const bf16x8*)(Wrow + k);
            bf16x8 a0 = *(const bf16x8*)(hb0 + k);
            bf16x8 a1 = *(const bf16x8*)(hb1 + k);
            acc0 = __builtin_amdgcn_mfma_f32_16x16x32_bf16(a0, bfrag, acc0, 0, 0, 0);
            acc1 = __builtin_amdgcn_mfma_f32_16x16x32_bf16(a1, bfrag, acc1, 0, 0, 0);
        }
        #pragma unroll
        for (int r = 0; r < 4; ++r) {
            pbuf[w][q * 4 + r][n] = acc0[r];
            pbuf[w][16 + q * 4 + r][n] = acc1[r];
        }
    }
    __syncthreads();
    {
        int b = t >> 4, nn = t & 15;
        int g = nn >> 2, jj = nn & 3;
        float s = bf2f(Xbf[(((size_t)step * 4 + g) * 32 + b) * 1024 + jbase + jj]);
        if (step > 0) {
            #pragma unroll
            for (int w2 = 0; w2 < 8; ++w2) s += pbuf[w2][b][nn];
        }
        sbuf[b][nn] = s;
    }
    __syncthreads();
    if (t < 128) {
        int b = t >> 2, jj = t & 3;
        float I  = sigf(sbuf[b][jj]);
        float Fg = sigf(sbuf[b][4 + jj]);
        float O  = sigf(sbuf[b][8 + jj]);
        float Ct = tanhf(sbuf[b][12 + jj]);
        float cprev = (step > 0) ? Cst[b * 1024 + jbase + jj] : 0.f;
        float c = fmaf(Fg, cprev, I * Ct);
        Cst[b * 1024 + jbase + jj] = c;
        float h = O * tanhf(c);
        if (step < 31) {
            Hnext[b * 1024 + jbase + jj] = bf16rne(h);
        } else {
            outH[b * 1024 + jbase + jj] = h;
        }
    }
}

extern "C" void kernel_launch(void* const* d_in, const int* in_sizes, int n_in,
                              void* d_out, int out_size, void* d_ws, size_t ws_size,
                              hipStream_t stream) {
    const float* F   = (const float*)d_in[0];
    const float* A   = (const float*)d_in[1];
    const float* C   = (const float*)d_in[2];
    const float* Wxi = (const float*)d_in[3];
    const float* bxi = (const float*)d_in[4];
    const float* Whi = (const float*)d_in[5];
    const float* bhi = (const float*)d_in[6];
    const float* Wxf = (const float*)d_in[7];
    const float* bxf = (const float*)d_in[8];
    const float* Whf = (const float*)d_in[9];
    const float* bhf = (const float*)d_in[10];
    const float* Wxo = (const float*)d_in[11];
    const float* bxo = (const float*)d_in[12];
    const float* Who = (const float*)d_in[13];
    const float* bho = (const float*)d_in[14];
    const float* Wxc = (const float*)d_in[15];
    const float* bxc = (const float*)d_in[16];
    const float* Whc = (const float*)d_in[17];
    const float* bhc = (const float*)d_in[18];

    float* out   = (float*)d_out;
    float* outH  = out;           // 32768
    float* outRC = out + 32768;   // 1
    float* outC  = out + 32769;   // 24576

    // ws layout (float units), total ~18.6 MB:
    // Xbf [0, 2097152) | P (Wxbf then Wbf) [2097152, 4194304) |
    // Vbf [4194304, 4587520) | part [4587520, 4587616) |
    // Hbf ping-pong [4587616, 4620384) | Cst [4620384, 4653152)
    float* ws = (float*)d_ws;
    unsigned short* Xbf  = (unsigned short*)ws;
    unsigned short* Wxbf = (unsigned short*)(ws + 2097152);  // aliased:
    unsigned short* Wbf  = (unsigned short*)(ws + 2097152);  // Wxbf dead before kPrep writes
    unsigned short* Vbf  = (unsigned short*)(ws + 4194304);
    float* part = ws + 4587520;
    unsigned short* Hbf = (unsigned short*)(ws + 4587616);
    float* Cst  = ws + 4620384;

    kA2<<<dim3(256), 256, 0, stream>>>(F, A, Vbf);
    kB1<<<dim3(96), 256, 0, stream>>>(Vbf, C, outC, part);
    kB2<<<1, 64, 0, stream>>>(part, outRC);
    kPrepX<<<dim3(1536), 256, 0, stream>>>(Wxi, Wxf, Wxo, Wxc, Wxbf);
    kC3<<<dim3(16, 32), 512, 0, stream>>>(Vbf, Wxbf,
                                          bxi, bxf, bxo, bxc,
                                          bhi, bhf, bho, bhc, Xbf);
    kPrep<<<dim3(2048), 256, 0, stream>>>(Whi, Whf, Who, Whc, Wbf);

    for (int step = 0; step < 32; ++step) {
        const unsigned short* Hprev = Hbf + ((step + 1) & 1) * 32768;
        unsigned short* Hnext = (unsigned short*)(Hbf + (step & 1) * 32768);
        kStep<<<dim3(256), 512, 0, stream>>>(Wbf, Xbf, Hprev, Hnext, Cst, outH, step);
    }
}

// Round 6
// 228.261 us; speedup vs baseline: 9.3515x; 1.1611x over previous
//
#include <hip/hip_runtime.h>
#include <math.h>

#define CF 768
#define MM 32
#define HW 784
#define MCF 24576
#define BETA 0.05f

typedef __attribute__((ext_vector_type(8))) short bf16x8;
typedef __attribute__((ext_vector_type(4))) float f32x4;

__device__ __forceinline__ unsigned short bf16rne(float x) {
    unsigned int bits = __float_as_uint(x);
    unsigned int r = (bits + 0x7fffu + ((bits >> 16) & 1u)) >> 16;
    return (unsigned short)r;
}
__device__ __forceinline__ float bf2f(unsigned short u) {
    return __uint_as_float(((unsigned int)u) << 16);
}
__device__ __forceinline__ float sigf(float x) { return 1.f / (1.f + __expf(-x)); }
__device__ __forceinline__ float ftanh(float x) {
    x = fminf(fmaxf(x, -12.f), 12.f);
    float e = __expf(2.f * x);
    return (e - 1.f) / (e + 1.f);
}

__device__ __forceinline__ void cvt8(const float4 a, const float4 b, unsigned short* u) {
    u[0] = bf16rne(a.x); u[1] = bf16rne(a.y); u[2] = bf16rne(a.z); u[3] = bf16rne(a.w);
    u[4] = bf16rne(b.x); u[5] = bf16rne(b.y); u[6] = bf16rne(b.z); u[7] = bf16rne(b.w);
}

// ================= kA3: MFMA einsum. V[b][m][c] = (1/784) sum_hw A[b][m][hw] F[b][c][hw]
// grid 384 = 32 b x 12 ctiles(64). 256 thr (4 waves, wave = n-tile of 16 c).
// K=784 zero-padded to 832 = 26 k-chunks of 32. A in frag-order LDS (once);
// F streamed in 64-k chunks (13), double-buffered, frag-order.
__global__ __launch_bounds__(256) void kA3(const float* __restrict__ F,
                                           const float* __restrict__ Ain,
                                           unsigned short* __restrict__ Vbf) {
    __shared__ unsigned short Alds[3328 * 8];      // 52 KB: slot16 = (kc*2+mt)*64+lane
    __shared__ unsigned short Flds[2][512 * 8];    // 2 x 8 KB: slot16 = (nt*2+kc2)*64+lane
    const int bid = blockIdx.x;
    const int b = bid / 12, ct = bid - b * 12;
    const int cbase = ct * 64;
    const int t = threadIdx.x;
    const int lane = t & 63, w = t >> 6;
    const int n = lane & 15, q = lane >> 4;

    // ---- A staging: slot s IS the target slot16 (linear writes, coalesced-ish reads)
    // decode: lf=s&63, mk=s>>6, mt=mk&1, kc=mk>>1, m=mt*16+(lf&15), k=kc*32+(lf>>4)*8
    {
        float4 va[7][2];
        #pragma unroll
        for (int it = 0; it < 7; ++it) {
            int s = it * 256 + t;
            int lf = s & 63, mk = s >> 6;
            int m = (mk & 1) * 16 + (lf & 15);
            int k = (mk >> 1) * 32 + (lf >> 4) * 8;
            if (k < 784) {
                const float* src = Ain + ((size_t)(b * 32 + m)) * 784 + k;
                va[it][0] = *(const float4*)src;
                va[it][1] = *(const float4*)(src + 4);
            } else {
                va[it][0] = (float4){0, 0, 0, 0};
                va[it][1] = (float4){0, 0, 0, 0};
            }
        }
        #pragma unroll
        for (int it = 0; it < 7; ++it) {
            int s = it * 256 + t;
            unsigned short u[8];
            cvt8(va[it][0], va[it][1], u);
            *(uint4*)&Alds[s * 8] = *(const uint4*)u;
        }
        float4 vb[6][2];
        #pragma unroll
        for (int it = 0; it < 6; ++it) {
            int s = (it + 7) * 256 + t;
            int lf = s & 63, mk = s >> 6;
            int m = (mk & 1) * 16 + (lf & 15);
            int k = (mk >> 1) * 32 + (lf >> 4) * 8;
            if (k < 784) {
                const float* src = Ain + ((size_t)(b * 32 + m)) * 784 + k;
                vb[it][0] = *(const float4*)src;
                vb[it][1] = *(const float4*)(src + 4);
            } else {
                vb[it][0] = (float4){0, 0, 0, 0};
                vb[it][1] = (float4){0, 0, 0, 0};
            }
        }
        #pragma unroll
        for (int it = 0; it < 6; ++it) {
            int s = (it + 7) * 256 + t;
            unsigned short u[8];
            cvt8(vb[it][0], vb[it][1], u);
            *(uint4*)&Alds[s * 8] = *(const uint4*)u;
        }
    }

    // ---- F chunk 0 prologue
    float4 pf[2][2];
    const int s0 = t, s1 = t + 256;
    const int ls0 = s0 & 63, kc20 = (s0 >> 6) & 1, nt0 = s0 >> 7;
    const int ls1 = s1 & 63, kc21 = (s1 >> 6) & 1, nt1 = s1 >> 7;
    const int fc0 = nt0 * 16 + (ls0 & 15), fk0 = kc20 * 32 + (ls0 >> 4) * 8;
    const int fc1 = nt1 * 16 + (ls1 & 15), fk1 = kc21 * 32 + (ls1 >> 4) * 8;
    const float* Fr0 = F + ((size_t)(b * 768) + cbase + fc0) * 784;
    const float* Fr1 = F + ((size_t)(b * 768) + cbase + fc1) * 784;
    pf[0][0] = *(const float4*)(Fr0 + fk0); pf[0][1] = *(const float4*)(Fr0 + fk0 + 4);
    pf[1][0] = *(const float4*)(Fr1 + fk1); pf[1][1] = *(const float4*)(Fr1 + fk1 + 4);
    {
        unsigned short u[8];
        cvt8(pf[0][0], pf[0][1], u); *(uint4*)&Flds[0][s0 * 8] = *(const uint4*)u;
        cvt8(pf[1][0], pf[1][1], u); *(uint4*)&Flds[0][s1 * 8] = *(const uint4*)u;
    }
    __syncthreads();

    f32x4 acc[2];
    acc[0] = (f32x4){0, 0, 0, 0};
    acc[1] = (f32x4){0, 0, 0, 0};

    for (int c13 = 0; c13 < 13; ++c13) {
        const int buf = c13 & 1;
        if (c13 < 12) {
            int k0 = (c13 + 1) * 64 + fk0;
            int k1 = (c13 + 1) * 64 + fk1;
            if (k0 < 784) {
                pf[0][0] = *(const float4*)(Fr0 + k0); pf[0][1] = *(const float4*)(Fr0 + k0 + 4);
            } else { pf[0][0] = (float4){0,0,0,0}; pf[0][1] = (float4){0,0,0,0}; }
            if (k1 < 784) {
                pf[1][0] = *(const float4*)(Fr1 + k1); pf[1][1] = *(const float4*)(Fr1 + k1 + 4);
            } else { pf[1][0] = (float4){0,0,0,0}; pf[1][1] = (float4){0,0,0,0}; }
        }
        #pragma unroll
        for (int kc2 = 0; kc2 < 2; ++kc2) {
            const int kc = c13 * 2 + kc2;
            bf16x8 bfr = *(const bf16x8*)&Flds[buf][((w * 2 + kc2) * 64 + lane) * 8];
            bf16x8 a0 = *(const bf16x8*)&Alds[((kc * 2 + 0) * 64 + lane) * 8];
            bf16x8 a1 = *(const bf16x8*)&Alds[((kc * 2 + 1) * 64 + lane) * 8];
            acc[0] = __builtin_amdgcn_mfma_f32_16x16x32_bf16(a0, bfr, acc[0], 0, 0, 0);
            acc[1] = __builtin_amdgcn_mfma_f32_16x16x32_bf16(a1, bfr, acc[1], 0, 0, 0);
        }
        if (c13 < 12) {
            unsigned short u[8];
            cvt8(pf[0][0], pf[0][1], u); *(uint4*)&Flds[buf ^ 1][s0 * 8] = *(const uint4*)u;
            cvt8(pf[1][0], pf[1][1], u); *(uint4*)&Flds[buf ^ 1][s1 * 8] = *(const uint4*)u;
        }
        __syncthreads();
    }

    #pragma unroll
    for (int mt = 0; mt < 2; ++mt)
        #pragma unroll
        for (int r = 0; r < 4; ++r)
            Vbf[(size_t)(b * 32 + mt * 16 + q * 4 + r) * 768 + cbase + w * 16 + n] =
                bf16rne(acc[mt][r] * (1.f / 784.f));
}

// ================= kMisc: kB1 (96 blocks) + prepX (1536) + prepH (2048)
__global__ __launch_bounds__(256) void kMisc(
    const unsigned short* __restrict__ Vbf, const float* __restrict__ C,
    float* __restrict__ Cnew_out, float* __restrict__ partial,
    const float* __restrict__ Wxi, const float* __restrict__ Wxf,
    const float* __restrict__ Wxo, const float* __restrict__ Wxc,
    unsigned short* __restrict__ Wxbf,
    const float* __restrict__ Whi, const float* __restrict__ Whf,
    const float* __restrict__ Who, const float* __restrict__ Whc,
    unsigned short* __restrict__ Wbf) {
    const int bid = blockIdx.x;
    if (bid < 96) {
        int j = bid * 256 + threadIdx.x;
        float c = C[j];
        float s = 0.f;
        for (int b = 0; b < 32; ++b) s += bf2f(Vbf[(size_t)b * MCF + j]);
        float cn = c + BETA * (s * (1.f / 32.f) - c);
        Cnew_out[j] = cn;
        float ds = 0.f;
        for (int b = 0; b < 32; ++b) {
            float d = bf2f(Vbf[(size_t)b * MCF + j]) - cn;
            ds = fmaf(d, d, ds);
        }
        __shared__ float red[256];
        red[threadIdx.x] = ds;
        __syncthreads();
        for (int off = 128; off > 0; off >>= 1) {
            if (threadIdx.x < off) red[threadIdx.x] += red[threadIdx.x + off];
            __syncthreads();
        }
        if (threadIdx.x == 0) partial[bid] = red[0];
    } else if (bid < 1632) {
        int gid = (bid - 96) * 256 + threadIdx.x;   // 393216
        int row = gid / 96;
        int kq = (gid - row * 96) * 8;
        int g = row >> 10, j = row & 1023;
        const float* Wg = (g == 0) ? Wxi : (g == 1) ? Wxf : (g == 2) ? Wxo : Wxc;
        const float* src = Wg + (size_t)j * CF + kq;
        float4 f0 = *(const float4*)src;
        float4 f1 = *(const float4*)(src + 4);
        unsigned short u[8];
        cvt8(f0, f1, u);
        *(uint4*)&Wxbf[(size_t)row * CF + kq] = *(const uint4*)u;
    } else {
        size_t tid8 = ((size_t)(bid - 1632) * 256 + threadIdx.x) * 8;
        int row = (int)(tid8 >> 10);
        int k = (int)(tid8 & 1023);
        int g = row >> 10, j = row & 1023;
        const float* Wg = (g == 0) ? Whi : (g == 1) ? Whf : (g == 2) ? Who : Whc;
        const float* src = Wg + (size_t)j * 1024 + k;
        float4 f0 = *(const float4*)src;
        float4 f1 = *(const float4*)(src + 4);
        unsigned short u[8];
        cvt8(f0, f1, u);
        *(uint4*)&Wbf[tid8] = *(const uint4*)u;
    }
}

// ================= kC3: MFMA GEMM  Xbf = bf16( Vt[1024x768] @ Wx^T[768x4096] + bias )
// + fused kB2 (rcloss final reduce) in block (0,31)
__global__ __launch_bounds__(512) void kC3(
    const unsigned short* __restrict__ Vbf,
    const unsigned short* __restrict__ Wxbf,
    const float* __restrict__ bxi, const float* __restrict__ bxf,
    const float* __restrict__ bxo, const float* __restrict__ bxc,
    const float* __restrict__ bhi, const float* __restrict__ bhf,
    const float* __restrict__ bho, const float* __restrict__ bhc,
    unsigned short* __restrict__ Xbf,
    const float* __restrict__ partial, float* __restrict__ outRC) {
    __shared__ unsigned short Asg[512 * 8];
    const int bx = blockIdx.x;
    const int by = blockIdx.y;
    const int t = threadIdx.x;
    const int lane = t & 63;
    const int w = t >> 6;
    const int n = lane & 15;
    const int q = lane >> 4;
    const int mbase = bx * 64;

    const int st_row = (w & 3) * 16 + n;
    const int st_kb  = (w >> 2) * 4 + q;
    const int st_rg  = mbase + st_row;
    const int st_vrow = (st_rg & 31) * 32 + (st_rg >> 5);
    const unsigned short* st_src = Vbf + (size_t)st_vrow * CF + st_kb * 8;

    const int nb = by * 128 + w * 16;
    const unsigned short* Brow = Wxbf + (size_t)(nb + n) * CF + q * 8;

    f32x4 acc[4];
    #pragma unroll
    for (int g = 0; g < 4; ++g) acc[g] = (f32x4){0.f, 0.f, 0.f, 0.f};

    uint4 st = *(const uint4*)st_src;
    for (int kc = 0; kc < 12; ++kc) {
        __syncthreads();
        *(uint4*)&Asg[t * 8] = st;
        __syncthreads();
        if (kc + 1 < 12) st = *(const uint4*)(st_src + (kc + 1) * 64);
        #pragma unroll
        for (int p = 0; p < 2; ++p) {
            bf16x8 bfr = *(const bf16x8*)(Brow + kc * 64 + p * 32);
            #pragma unroll
            for (int g = 0; g < 4; ++g) {
                bf16x8 a = *(const bf16x8*)&Asg[((p * 4 + g) * 64 + lane) * 8];
                acc[g] = __builtin_amdgcn_mfma_f32_16x16x32_bf16(a, bfr, acc[g], 0, 0, 0);
            }
        }
    }

    const int gg = by >> 3;
    const int j = (by & 7) * 128 + w * 16 + n;
    const float* bx_ = (gg == 0) ? bxi : (gg == 1) ? bxf : (gg == 2) ? bxo : bxc;
    const float* bh_ = (gg == 0) ? bhi : (gg == 1) ? bhf : (gg == 2) ? bho : bhc;
    const float bias = bx_[j] + bh_[j];
    #pragma unroll
    for (int g = 0; g < 4; ++g) {
        #pragma unroll
        for (int rr = 0; rr < 4; ++rr) {
            int rg = mbase + g * 16 + q * 4 + rr;
            int tt = rg >> 5, bb = rg & 31;
            Xbf[((size_t)(tt * 4 + gg) * 32 + bb) * 1024 + j] = bf16rne(acc[g][rr] + bias);
        }
    }

    // fused kB2: final rcloss reduce (uses Asg as f32 scratch)
    if (bx == 0 && by == 31) {
        __syncthreads();
        float* red = (float*)Asg;
        float v = (t < 96) ? partial[t] : 0.f;
        red[t] = v;
        __syncthreads();
        for (int off = 256; off > 0; off >>= 1) {
            if (t < off) red[t] += red[t + off];
            __syncthreads();
        }
        if (t == 0) outRC[0] = red[0] / (32.f * 24576.f);
    }
}

// ================= kStep: one LSTM step. 256 blocks x 512 thr (8 waves).
__global__ __launch_bounds__(512) void kStep(
    const unsigned short* __restrict__ Wbf,
    const unsigned short* __restrict__ Xbf,
    const unsigned short* __restrict__ Hprev,
    unsigned short* __restrict__ Hnext,
    float* __restrict__ Cst,
    float* __restrict__ outH,
    int step) {
    __shared__ float pbuf[8][32][17];
    __shared__ float sbuf[32][17];
    const int bi = blockIdx.x;
    const int jbase = bi * 4;
    const int t = threadIdx.x;
    const int lane = t & 63;
    const int w = t >> 6;
    const int n = lane & 15;
    const int q = lane >> 4;

    // prefetch (off the critical path): Xpre value + cell state
    const int pb = t >> 4, pnn = t & 15;
    const int pg = pnn >> 2, pjj = pnn & 3;
    const float xv = bf2f(Xbf[(((size_t)step * 4 + pg) * 32 + pb) * 1024 + jbase + pjj]);
    float cprev = 0.f;
    if (step > 0 && t < 128) cprev = Cst[(t >> 2) * 1024 + jbase + (t & 3)];

    if (step > 0) {
        const int g = n >> 2, jj = n & 3;
        const unsigned short* Wrow = Wbf + ((size_t)(g * 1024 + jbase + jj)) * 1024 + w * 128;
        const unsigned short* hb0 = Hprev + (size_t)n * 1024 + w * 128;
        const unsigned short* hb1 = Hprev + (size_t)(n + 16) * 1024 + w * 128;
        f32x4 acc0 = {0.f, 0.f, 0.f, 0.f};
        f32x4 acc1 = {0.f, 0.f, 0.f, 0.f};
        #pragma unroll
        for (int ks = 0; ks < 4; ++ks) {
            int k = ks * 32 + q * 8;
            bf16x8 bfrag = *(const bf16x8*)(Wrow + k);
            bf16x8 a0 = *(const bf16x8*)(hb0 + k);
            bf16x8 a1 = *(const bf16x8*)(hb1 + k);
            acc0 = __builtin_amdgcn_mfma_f32_16x16x32_bf16(a0, bfrag, acc0, 0, 0, 0);
            acc1 = __builtin_amdgcn_mfma_f32_16x16x32_bf16(a1, bfrag, acc1, 0, 0, 0);
        }
        #pragma unroll
        for (int r = 0; r < 4; ++r) {
            pbuf[w][q * 4 + r][n] = acc0[r];
            pbuf[w][16 + q * 4 + r][n] = acc1[r];
        }
    }
    __syncthreads();
    {
        float s = xv;
        if (step > 0) {
            #pragma unroll
            for (int w2 = 0; w2 < 8; ++w2) s += pbuf[w2][pb][pnn];
        }
        sbuf[pb][pnn] = s;
    }
    __syncthreads();
    if (t < 128) {
        int b = t >> 2, jj = t & 3;
        float I  = sigf(sbuf[b][jj]);
        float Fg = sigf(sbuf[b][4 + jj]);
        float O  = sigf(sbuf[b][8 + jj]);
        float Ct = ftanh(sbuf[b][12 + jj]);
        float c = fmaf(Fg, cprev, I * Ct);
        Cst[b * 1024 + jbase + jj] = c;
        float h = O * ftanh(c);
        if (step < 31) {
            Hnext[b * 1024 + jbase + jj] = bf16rne(h);
        } else {
            outH[b * 1024 + jbase + jj] = h;
        }
    }
}

extern "C" void kernel_launch(void* const* d_in, const int* in_sizes, int n_in,
                              void* d_out, int out_size, void* d_ws, size_t ws_size,
                              hipStream_t stream) {
    const float* F   = (const float*)d_in[0];
    const float* A   = (const float*)d_in[1];
    const float* C   = (const float*)d_in[2];
    const float* Wxi = (const float*)d_in[3];
    const float* bxi = (const float*)d_in[4];
    const float* Whi = (const float*)d_in[5];
    const float* bhi = (const float*)d_in[6];
    const float* Wxf = (const float*)d_in[7];
    const float* bxf = (const float*)d_in[8];
    const float* Whf = (const float*)d_in[9];
    const float* bhf = (const float*)d_in[10];
    const float* Wxo = (const float*)d_in[11];
    const float* bxo = (const float*)d_in[12];
    const float* Who = (const float*)d_in[13];
    const float* bho = (const float*)d_in[14];
    const float* Wxc = (const float*)d_in[15];
    const float* bxc = (const float*)d_in[16];
    const float* Whc = (const float*)d_in[17];
    const float* bhc = (const float*)d_in[18];

    float* out   = (float*)d_out;
    float* outH  = out;           // 32768
    float* outRC = out + 32768;   // 1
    float* outC  = out + 32769;   // 24576

    // ws layout (float units), total ~24.9 MB:
    float* ws = (float*)d_ws;
    unsigned short* Xbf  = (unsigned short*)ws;                  // [0, 2097152)
    unsigned short* Wxbf = (unsigned short*)(ws + 2097152);      // [2097152, 3670016)
    unsigned short* Wbf  = (unsigned short*)(ws + 3670016);      // [3670016, 5767168)
    unsigned short* Vbf  = (unsigned short*)(ws + 5767168);      // [5767168, 6160384)
    float* part = ws + 6160384;                                  // 96
    unsigned short* Hbf = (unsigned short*)(ws + 6160480);       // 2 x 32768 us
    float* Cst  = ws + 6193248;                                  // 32768

    kA3<<<dim3(384), 256, 0, stream>>>(F, A, Vbf);
    kMisc<<<dim3(3680), 256, 0, stream>>>(Vbf, C, outC, part,
                                          Wxi, Wxf, Wxo, Wxc, Wxbf,
                                          Whi, Whf, Who, Whc, Wbf);
    kC3<<<dim3(16, 32), 512, 0, stream>>>(Vbf, Wxbf,
                                          bxi, bxf, bxo, bxc,
                                          bhi, bhf, bho, bhc, Xbf,
                                          part, outRC);

    for (int step = 0; step < 32; ++step) {
        const unsigned short* Hprev = Hbf + ((step + 1) & 1) * 32768;
        unsigned short* Hnext = (unsigned short*)(Hbf + (step & 1) * 32768);
        kStep<<<dim3(256), 512, 0, stream>>>(Wbf, Xbf, Hprev, Hnext, Cst, outH, step);
    }
}